// Round 5
// baseline (319.591 us; speedup 1.0000x reference)
//
#include <hip/hip_runtime.h>
#include <stdint.h>

#define IN_F 4096
#define OUT_F 4096
#define NROWS 8192

typedef __attribute__((ext_vector_type(4))) int int4v;
typedef __attribute__((ext_vector_type(8))) int int8v;
typedef __attribute__((ext_vector_type(16))) float f32x16;

// ---- kernel 1: fp8-quantize x AND partial spline dot-products s = x . CP^T ----
// grid 2048 = 256 row-groups x 8 col-chunks; 256 thr; 32 rows x 512 cols per block.
__global__ __launch_bounds__(256) void xq_s(const float* __restrict__ x,
                                            const float* __restrict__ cp,
                                            unsigned char* __restrict__ xb,
                                            float* __restrict__ ps) {
  __shared__ float4 cps[9 * 128];
  const int b = blockIdx.x;
  const int rg = b >> 3, ck = b & 7;
  const int tid = threadIdx.x;
  for (int i = tid; i < 9 * 128; i += 256) {
    const int j = i >> 7, c = i & 127;
    cps[i] = ((const float4*)(cp + (size_t)j * IN_F + ck * 512))[c];
  }
  __syncthreads();
  const int row = rg * 32 + (tid >> 3);
  const int c0 = ck * 512 + (tid & 7) * 64;
  const float4* xr = (const float4*)(x + (size_t)row * IN_F + c0);
  uint32_t* xo = (uint32_t*)(xb + (size_t)row * IN_F + c0);
  float p[9] = {0, 0, 0, 0, 0, 0, 0, 0, 0};
  #pragma unroll 4
  for (int g = 0; g < 16; ++g) {
    float4 v = xr[g];
    const int cc = (tid & 7) * 16 + g;
    #pragma unroll
    for (int j = 0; j < 9; ++j) {
      float4 w = cps[j * 128 + cc];
      p[j] += v.x * w.x + v.y * w.y + v.z * w.z + v.w * w.w;
    }
    int pk = __builtin_amdgcn_cvt_pk_fp8_f32(v.x, v.y, 0, false);
    pk = __builtin_amdgcn_cvt_pk_fp8_f32(v.z, v.w, pk, true);
    xo[g] = (uint32_t)pk;
  }
  #pragma unroll
  for (int j = 0; j < 9; ++j) {
    float v = p[j];
    v += __shfl_xor(v, 1);
    v += __shfl_xor(v, 2);
    v += __shfl_xor(v, 4);
    p[j] = v;
  }
  if ((tid & 7) == 0) {
    float* outp = ps + ((size_t)row * 8 + ck) * 9;
    #pragma unroll
    for (int j = 0; j < 9; ++j) outp[j] = p[j];
  }
}

// ---- kernel 2: reduce 8 chunk-partials -> s[8192][9] (deterministic) ----
__global__ void s_reduce(const float* __restrict__ ps, float* __restrict__ s) {
  const int row = blockIdx.x * 256 + threadIdx.x;
  const float* pr = ps + (size_t)row * 72;
  #pragma unroll
  for (int j = 0; j < 9; ++j) {
    float v = 0.f;
    #pragma unroll
    for (int k = 0; k < 8; ++k) v += pr[k * 9 + j];
    s[row * 9 + j] = v;
  }
}

// ---- kernel 3: resid * 64 -> fp8 e4m3 ----
__global__ __launch_bounds__(256) void rq(const float* __restrict__ r,
                                          unsigned char* __restrict__ rb) {
  const int i = blockIdx.x * 256 + threadIdx.x;   // 16 elems each
  const float4* rv = (const float4*)r + (size_t)i * 4;
  uint32_t pk4[4];
  #pragma unroll
  for (int g = 0; g < 4; ++g) {
    float4 v = rv[g];
    int pk = __builtin_amdgcn_cvt_pk_fp8_f32(v.x * 64.f, v.y * 64.f, 0, false);
    pk = __builtin_amdgcn_cvt_pk_fp8_f32(v.z * 64.f, v.w * 64.f, pk, true);
    pk4[g] = (uint32_t)pk;
  }
  ((uint4*)rb)[i] = make_uint4(pk4[0], pk4[1], pk4[2], pk4[3]);
}

#define MFMA_FP8(d, av, bv) \
  d = __builtin_amdgcn_mfma_scale_f32_32x32x64_f8f6f4( \
      av, bv, d, 0, 0, 0, 0x7F7F7F7F, 0, 0x7F7F7F7F)

// ---- kernel 4: y = (xb . rb^T)/64 + spline(s) + bias ----
// 128x128 tile, BK=64, 4 waves (2x2, 64x64 each), mfma_scale 32x32x64 fp8,
// dbuf LDS 32 KB -> 4 blocks/CU. LDS rows = 128 B (two fp8-rows packed),
// 16B-slot XOR swizzle (slot ^= ldsrow&7) both-sides: inverse-swizzled global
// source for linear global_load_lds dest + swizzled ds_read. One barrier/iter.
__global__ __launch_bounds__(256, 4) void gemm_fp8(
    const unsigned char* __restrict__ A,   // xb [8192][4096]
    const unsigned char* __restrict__ B,   // rb [4096][4096] (x64)
    const float* __restrict__ S,           // s [8192][9]
    const float* __restrict__ bias,
    float* __restrict__ C) {
  __shared__ unsigned char lds[2][2][64 * 128];   // [buf][A|B] = 32 KiB

  const int tid = threadIdx.x;
  const int lane = tid & 63;
  const int wave = tid >> 6;    // 0..3
  const int wr = wave >> 1;     // M half of tile
  const int wn = wave & 1;      // N half
  const int l31 = lane & 31;
  const int lh = lane >> 5;

  // XCD-aware swizzle (2048 blocks % 8 == 0 -> simple form bijective)
  const int bs = (blockIdx.x & 7) * 256 + (blockIdx.x >> 3);
  const int bm = bs >> 5;       // 64 M-tiles
  const int bn = bs & 31;       // 32 N-tiles
  const size_t row0 = (size_t)bm * 128;
  const size_t col0 = (size_t)bn * 128;

  // stage 64 fp8-rows [half*64, half*64+64) of A/B K-tile kt -> buf
  auto stage = [&](int buf, int ab, int half, const unsigned char* __restrict__ src,
                   size_t grow0, int kt) {
    const int ls = (tid & 7) ^ ((tid >> 3) & 7);           // logical 16B slot
    const int r = half * 64 + 2 * (tid >> 3) + (ls >> 2);  // fp8 row
    const unsigned char* g = src + (grow0 + r) * (size_t)IN_F + kt * 64 + (ls & 3) * 16;
    unsigned char* d = &lds[buf][ab][half * 4096] + (tid >> 6) * 1024;
    __builtin_amdgcn_global_load_lds(
        (const __attribute__((address_space(1))) void*)g,
        (__attribute__((address_space(3))) void*)d, 16, 0, 0);
  };
  // read one b128 of a 32-row fragment: row rbase+l31, k-half lh, sub s2
  auto ldf = [&](int buf, int ab, int rbase, int s2) -> int4v {
    const int r = rbase + l31;
    const int sl = (r & 1) * 4 + lh * 2 + s2;
    const int L = r >> 1;
    return *(const int4v*)&lds[buf][ab][L * 128 + ((sl ^ (L & 7)) * 16)];
  };

  f32x16 acc[2][2] = {};

  stage(0, 0, 0, A, row0, 0); stage(0, 0, 1, A, row0, 0);
  stage(0, 1, 0, B, col0, 0); stage(0, 1, 1, B, col0, 0);
  __syncthreads();

  for (int kt = 0; kt < IN_F / 64; ++kt) {
    const int c = kt & 1;
    if (kt + 1 < IN_F / 64) {
      stage(c ^ 1, 0, 0, A, row0, kt + 1); stage(c ^ 1, 0, 1, A, row0, kt + 1);
      stage(c ^ 1, 1, 0, B, col0, kt + 1); stage(c ^ 1, 1, 1, B, col0, kt + 1);
    }
    union { int8v v8; int4v v4[2]; } a0, a1, b0, b1;
    a0.v4[0] = ldf(c, 0, wr * 64 + 0,  0); a0.v4[1] = ldf(c, 0, wr * 64 + 0,  1);
    a1.v4[0] = ldf(c, 0, wr * 64 + 32, 0); a1.v4[1] = ldf(c, 0, wr * 64 + 32, 1);
    b0.v4[0] = ldf(c, 1, wn * 64 + 0,  0); b0.v4[1] = ldf(c, 1, wn * 64 + 0,  1);
    b1.v4[0] = ldf(c, 1, wn * 64 + 32, 0); b1.v4[1] = ldf(c, 1, wn * 64 + 32, 1);
    __builtin_amdgcn_s_setprio(1);
    MFMA_FP8(acc[0][0], a0.v8, b0.v8);
    MFMA_FP8(acc[0][1], a0.v8, b1.v8);
    MFMA_FP8(acc[1][0], a1.v8, b0.v8);
    MFMA_FP8(acc[1][1], a1.v8, b1.v8);
    __builtin_amdgcn_s_setprio(0);
    __syncthreads();
  }

  // epilogue: y = acc/64 + Catmull-Rom(o) . s[n][j-1..j+2] + bias[o]
  // D layout (32x32): col = lane&31, row = (reg&3) + 8*(reg>>2) + 4*(lane>>5)
  const float inv64 = 0.015625f;
  #pragma unroll
  for (int ni = 0; ni < 2; ++ni) {
    const int o = (int)col0 + wn * 64 + ni * 32 + l31;
    float ts = ((float)o / 4095.0f) * 8.0f;
    int j = (int)floorf(ts);
    j = j < 1 ? 1 : (j > 6 ? 6 : j);
    float t = ts - (float)j;
    float t2 = t * t, t3 = t2 * t;
    const float c0 = -0.5f * t3 + t2 - 0.5f * t;
    const float c1 = 1.5f * t3 - 2.5f * t2 + 1.0f;
    const float c2 = -1.5f * t3 + 2.0f * t2 + 0.5f * t;
    const float c3 = 0.5f * t3 - 0.5f * t2;
    const float bv = bias[o];
    #pragma unroll
    for (int mi = 0; mi < 2; ++mi) {
      #pragma unroll
      for (int rg = 0; rg < 16; ++rg) {
        const int n = (int)row0 + wr * 64 + mi * 32 + (rg & 3) + 8 * (rg >> 2) + 4 * lh;
        const float* sr = S + n * 9 + (j - 1);
        C[(size_t)n * OUT_F + o] =
            acc[mi][ni][rg] * inv64 + c0 * sr[0] + c1 * sr[1] + c2 * sr[2] + c3 * sr[3] + bv;
      }
    }
  }
}

// ---- safety net: fp32 tiled GEMM w/ on-the-fly weight ----
static __device__ __forceinline__ void cr_coeffs(int o, int& j, float& c0, float& c1,
                                                 float& c2, float& c3) {
  float ts = ((float)o / 4095.0f) * 8.0f;
  j = (int)floorf(ts);
  j = j < 1 ? 1 : (j > 6 ? 6 : j);
  float t = ts - (float)j;
  float t2 = t * t, t3 = t2 * t;
  c0 = -0.5f * t3 + t2 - 0.5f * t;
  c1 = 1.5f * t3 - 2.5f * t2 + 1.0f;
  c2 = -1.5f * t3 + 2.0f * t2 + 0.5f * t;
  c3 = 0.5f * t3 - 0.5f * t2;
}

__global__ void fallback_gemm(const float* __restrict__ x, const float* __restrict__ cp,
                              const float* __restrict__ resid, const float* __restrict__ bias,
                              float* __restrict__ out) {
  __shared__ float xs[64][32];
  __shared__ float ws[64][33];
  const int tid = threadIdx.x;
  const int bm = blockIdx.x / (OUT_F / 64);
  const int bn = blockIdx.x % (OUT_F / 64);
  const int row0 = bm * 64, col0 = bn * 64;
  const int tr = tid >> 4, tc = tid & 15;
  float acc[4][4] = {};
  for (int k0 = 0; k0 < IN_F; k0 += 32) {
    #pragma unroll
    for (int q = 0; q < 8; ++q) {
      int e = q * 256 + tid;
      int r = e >> 5, cc = e & 31;
      xs[r][cc] = x[(size_t)(row0 + r) * IN_F + k0 + cc];
      int o = col0 + r;
      int j; float c0, c1, c2, c3;
      cr_coeffs(o, j, c0, c1, c2, c3);
      size_t ci = (size_t)(j - 1) * IN_F + k0 + cc;
      ws[r][cc] = c0 * cp[ci] + c1 * cp[ci + IN_F] + c2 * cp[ci + 2 * IN_F] +
                  c3 * cp[ci + 3 * IN_F] + resid[(size_t)o * IN_F + k0 + cc];
    }
    __syncthreads();
    #pragma unroll
    for (int kk = 0; kk < 32; ++kk) {
      float xv[4], wv[4];
      #pragma unroll
      for (int i = 0; i < 4; ++i) xv[i] = xs[tr * 4 + i][kk];
      #pragma unroll
      for (int i = 0; i < 4; ++i) wv[i] = ws[tc * 4 + i][kk];
      #pragma unroll
      for (int i = 0; i < 4; ++i)
        #pragma unroll
        for (int jj = 0; jj < 4; ++jj) acc[i][jj] += xv[i] * wv[jj];
    }
    __syncthreads();
  }
  #pragma unroll
  for (int i = 0; i < 4; ++i)
    #pragma unroll
    for (int jj = 0; jj < 4; ++jj) {
      int row = row0 + tr * 4 + i, col = col0 + tc * 4 + jj;
      out[(size_t)row * OUT_F + col] = acc[i][jj] + bias[col];
    }
}

extern "C" void kernel_launch(void* const* d_in, const int* in_sizes, int n_in,
                              void* d_out, int out_size, void* d_ws, size_t ws_size,
                              hipStream_t stream) {
  const float* x = (const float*)d_in[0];
  const float* cp = (const float*)d_in[1];
  const float* resid = (const float*)d_in[2];
  const float* bias = (const float*)d_in[3];
  float* out = (float*)d_out;

  const size_t xb_b = (size_t)NROWS * IN_F;        // 33,554,432
  const size_t rb_b = (size_t)OUT_F * IN_F;        // 16,777,216
  const size_t s_b = (size_t)NROWS * 9 * 4;        // 294,912
  const size_t ps_b = (size_t)NROWS * 72 * 4;      // 2,359,296

  if (ws_size >= xb_b + rb_b + s_b + ps_b) {
    unsigned char* xb = (unsigned char*)d_ws;
    unsigned char* rb = xb + xb_b;
    float* s = (float*)(rb + rb_b);
    float* ps = (float*)((unsigned char*)s + s_b);
    hipLaunchKernelGGL(xq_s, dim3(2048), dim3(256), 0, stream, x, cp, xb, ps);
    hipLaunchKernelGGL(s_reduce, dim3(32), dim3(256), 0, stream, ps, s);
    hipLaunchKernelGGL(rq, dim3(4096), dim3(256), 0, stream, resid, rb);
    hipLaunchKernelGGL(gemm_fp8, dim3(2048), dim3(256), 0, stream, xb, rb, s, bias, out);
  } else {
    hipLaunchKernelGGL(fallback_gemm, dim3((NROWS / 64) * (OUT_F / 64)), dim3(256), 0,
                       stream, x, cp, resid, bias, out);
  }
}